// Round 1
// baseline (658.530 us; speedup 1.0000x reference)
//
#include <hip/hip_runtime.h>
#include <hip/hip_bf16.h>
#include <stdint.h>

// ---------------------------------------------------------------------------
// MHA: out = (softmax((xWq^T)(xWk^T)^T / 8) (xWv^T)) Wo^T  + attn matrix out
// B=4 S=1024 H=16 D=64 DM=1024.
// d_out = [ out (B,S,DM) fp32 | attn (B,H,S,S) fp32 ]
// ws    = [ Qb (B,H,S,D) bf16 | Kb (B,H,S,D) bf16 | Vt (B,H,D,S) bf16 |
//           ctx (B,S,DM) bf16 ]   (4 x 8 MB = 32 MB)
// ---------------------------------------------------------------------------

#define DEV static __device__ __forceinline__

typedef __bf16 bf16x8 __attribute__((ext_vector_type(8)));
typedef float f32x4 __attribute__((ext_vector_type(4)));
typedef unsigned short u16x8 __attribute__((ext_vector_type(8)));

static constexpr int B = 4, S = 1024, H = 16, D = 64, DM = 1024;
static constexpr int M = B * S; // 4096

DEV uint16_t f2bf_bits(float f) {
    __hip_bfloat16 h = __float2bfloat16(f); // RNE
    return __builtin_bit_cast(uint16_t, h);
}

DEV bf16x8 ldfrag(const uint16_t* p) { // p must be 16B aligned
    u16x8 t = *(const u16x8*)p;
    return __builtin_bit_cast(bf16x8, t);
}

// ---------------------------------------------------------------------------
// GEMM: C[m,n] = sum_k A[m,k] * W[n,k]   (i.e. A @ W^T), M=4096 N=1024 K=1024
// SRC_F32: A is fp32 (else bf16 in ws).  W always fp32.
// OUT_MODE 0: bf16 -> (B,H,S,D)   (Q,K projections)
// OUT_MODE 1: bf16 -> (B,H,D,S)   (V projection, transposed for PV step)
// OUT_MODE 2: fp32 -> row-major (M,DM)   (final output GEMM)
// ---------------------------------------------------------------------------
template <int SRC_F32, int OUT_MODE>
__global__ __launch_bounds__(256) void gemm_bt(const void* __restrict__ Ap,
                                               const float* __restrict__ W,
                                               void* __restrict__ Cp) {
    constexpr int BM = 128, BN = 128, BK = 32, LDT = 40; // pad 32->40 (bank-safe)
    __shared__ uint16_t Ah[BM][LDT];
    __shared__ uint16_t Bh[BN][LDT];
    const int tid = threadIdx.x;
    const int lane = tid & 63, wid = tid >> 6;
    const int lr = lane & 15, lg = lane >> 4;
    const int m0 = blockIdx.x * BM, n0 = blockIdx.y * BN;
    const int wr = (wid >> 1) * 64, wc = (wid & 1) * 64;

    f32x4 acc[4][4] = {};

    for (int kb = 0; kb < DM / BK; ++kb) {
        __syncthreads();
        // ---- stage A tile (128 x 32) ----
        if (SRC_F32) {
            const float* A = (const float*)Ap;
#pragma unroll
            for (int i = 0; i < 4; ++i) {
                int idx = tid + i * 256; // float4 id, 1024 total
                int row = idx >> 3, c4 = (idx & 7) * 4;
                float4 v = *(const float4*)(A + (size_t)(m0 + row) * DM + kb * BK + c4);
                uint64_t pk = (uint64_t)f2bf_bits(v.x) | ((uint64_t)f2bf_bits(v.y) << 16) |
                              ((uint64_t)f2bf_bits(v.z) << 32) | ((uint64_t)f2bf_bits(v.w) << 48);
                *(uint64_t*)&Ah[row][c4] = pk;
            }
        } else {
            const uint16_t* A = (const uint16_t*)Ap;
#pragma unroll
            for (int i = 0; i < 2; ++i) {
                int idx = tid + i * 256; // 16B id, 512 total
                int row = idx >> 2, c8 = (idx & 3) * 8;
                *(u16x8*)&Ah[row][c8] = *(const u16x8*)(A + (size_t)(m0 + row) * DM + kb * BK + c8);
            }
        }
        // ---- stage W tile (128 x 32), always fp32 ----
#pragma unroll
        for (int i = 0; i < 4; ++i) {
            int idx = tid + i * 256;
            int row = idx >> 3, c4 = (idx & 7) * 4;
            float4 v = *(const float4*)(W + (size_t)(n0 + row) * DM + kb * BK + c4);
            uint64_t pk = (uint64_t)f2bf_bits(v.x) | ((uint64_t)f2bf_bits(v.y) << 16) |
                          ((uint64_t)f2bf_bits(v.z) << 32) | ((uint64_t)f2bf_bits(v.w) << 48);
            *(uint64_t*)&Bh[row][c4] = pk;
        }
        __syncthreads();

        bf16x8 af[4], bw[4];
#pragma unroll
        for (int i = 0; i < 4; ++i) af[i] = ldfrag(&Ah[wr + i * 16 + lr][lg * 8]);
#pragma unroll
        for (int i = 0; i < 4; ++i) bw[i] = ldfrag(&Bh[wc + i * 16 + lr][lg * 8]);
#pragma unroll
        for (int mi = 0; mi < 4; ++mi)
#pragma unroll
            for (int ni = 0; ni < 4; ++ni)
                acc[mi][ni] = __builtin_amdgcn_mfma_f32_16x16x32_bf16(af[mi], bw[ni], acc[mi][ni], 0, 0, 0);
    }

    // ---- epilogue: C/D layout col=lane&15, row=(lane>>4)*4+r (HW-verified) ----
#pragma unroll
    for (int mi = 0; mi < 4; ++mi)
#pragma unroll
        for (int ni = 0; ni < 4; ++ni)
#pragma unroll
            for (int r = 0; r < 4; ++r) {
                int gm = m0 + wr + mi * 16 + lg * 4 + r;
                int gn = n0 + wc + ni * 16 + lr;
                float v = acc[mi][ni][r];
                if (OUT_MODE == 0) {
                    int b = gm >> 10, s = gm & 1023, h = gn >> 6, d = gn & 63;
                    ((uint16_t*)Cp)[((size_t)(b * H + h) * S + s) * D + d] = f2bf_bits(v);
                } else if (OUT_MODE == 1) {
                    int b = gm >> 10, s = gm & 1023, h = gn >> 6, d = gn & 63;
                    ((uint16_t*)Cp)[((size_t)(b * H + h) * D + d) * S + s] = f2bf_bits(v);
                } else {
                    ((float*)Cp)[(size_t)gm * DM + gn] = v;
                }
            }
}

// ---------------------------------------------------------------------------
// Fused attention: per block = one (b,h) and 64 Q rows; 4 waves x 16 rows.
// Pass 1: row sums of exp(s)  (no max-subtract: |s| <~ 2.5, fp32 safe).
// Pass 2: recompute s, p = exp(s)/l; write attn fp32; LDS C->A frag shuffle;
//         PV MFMA into ctx accumulators; store ctx bf16 (B,S,DM).
// ---------------------------------------------------------------------------
__global__ __launch_bounds__(256) void attn_fused(const uint16_t* __restrict__ Qb,
                                                  const uint16_t* __restrict__ Kb,
                                                  const uint16_t* __restrict__ Vt,
                                                  float* __restrict__ attn,
                                                  uint16_t* __restrict__ ctx) {
    __shared__ uint16_t plds[4][16][40]; // per-wave 16 q-rows x 32 keys (pad->40)
    const int tid = threadIdx.x, lane = tid & 63, wid = tid >> 6;
    const int lr = lane & 15, lg = lane >> 4;
    const int qt = blockIdx.x, bh = blockIdx.y;
    const int q0 = qt * 64 + wid * 16;

    // Q fragments (rows q0..q0+15, k-halves 0-31 / 32-63)
    const uint16_t* Qp = Qb + ((size_t)bh * S + q0) * D;
    const bf16x8 aq0 = ldfrag(Qp + lr * D + lg * 8);
    const bf16x8 aq1 = ldfrag(Qp + lr * D + 32 + lg * 8);

    const uint16_t* Kbase = Kb + (size_t)bh * S * D;
    constexpr float CEXP = 0.125f * 1.44269504088896340736f; // (1/sqrt(D)) * log2(e)

    // ---- pass 1: l[row] = sum_k exp(s) ----
    float lsum[4] = {0.f, 0.f, 0.f, 0.f};
    for (int kc = 0; kc < S / 16; ++kc) {
        const uint16_t* Kp = Kbase + (size_t)kc * 16 * D;
        bf16x8 bk0 = ldfrag(Kp + lr * D + lg * 8);
        bf16x8 bk1 = ldfrag(Kp + lr * D + 32 + lg * 8);
        f32x4 sacc = {};
        sacc = __builtin_amdgcn_mfma_f32_16x16x32_bf16(aq0, bk0, sacc, 0, 0, 0);
        sacc = __builtin_amdgcn_mfma_f32_16x16x32_bf16(aq1, bk1, sacc, 0, 0, 0);
#pragma unroll
        for (int r = 0; r < 4; ++r) lsum[r] += exp2f(sacc[r] * CEXP);
    }
    // reduce across the 16-lane col group; then invert
#pragma unroll
    for (int r = 0; r < 4; ++r) {
        float v = lsum[r];
        v += __shfl_xor(v, 1);
        v += __shfl_xor(v, 2);
        v += __shfl_xor(v, 4);
        v += __shfl_xor(v, 8);
        lsum[r] = 1.0f / v;
    }

    // ---- pass 2: attn write + PV ----
    f32x4 cacc[4] = {};
    float* attn_base = attn + (size_t)bh * S * S + (size_t)q0 * S;
    const uint16_t* Vbase = Vt + (size_t)bh * D * S;
    uint16_t(*pw)[40] = plds[wid];

    for (int kc = 0; kc < S / 32; ++kc) {
#pragma unroll
        for (int t = 0; t < 2; ++t) {
            const uint16_t* Kp = Kbase + (size_t)(kc * 32 + t * 16) * D;
            bf16x8 bk0 = ldfrag(Kp + lr * D + lg * 8);
            bf16x8 bk1 = ldfrag(Kp + lr * D + 32 + lg * 8);
            f32x4 sacc = {};
            sacc = __builtin_amdgcn_mfma_f32_16x16x32_bf16(aq0, bk0, sacc, 0, 0, 0);
            sacc = __builtin_amdgcn_mfma_f32_16x16x32_bf16(aq1, bk1, sacc, 0, 0, 0);
#pragma unroll
            for (int r = 0; r < 4; ++r) {
                float p = exp2f(sacc[r] * CEXP) * lsum[r]; // normalized prob
                attn_base[(size_t)(lg * 4 + r) * S + kc * 32 + t * 16 + lr] = p;
                pw[lg * 4 + r][t * 16 + lr] = f2bf_bits(p);
            }
        }
        // wave-private LDS: drain ds writes before cross-lane read
        asm volatile("s_waitcnt lgkmcnt(0)" ::: "memory");
        bf16x8 pa = ldfrag(&pw[lr][lg * 8]); // A-frag: row=q, k=32 keys of chunk
#pragma unroll
        for (int dt = 0; dt < 4; ++dt) {
            bf16x8 bv = ldfrag(Vbase + (size_t)(dt * 16 + lr) * S + kc * 32 + lg * 8);
            cacc[dt] = __builtin_amdgcn_mfma_f32_16x16x32_bf16(pa, bv, cacc[dt], 0, 0, 0);
        }
    }

    // ---- ctx store: (B,S,DM) bf16 ----
    const int b = bh >> 4, h = bh & 15;
#pragma unroll
    for (int dt = 0; dt < 4; ++dt)
#pragma unroll
        for (int r = 0; r < 4; ++r) {
            int q = q0 + lg * 4 + r;
            int d = dt * 16 + lr;
            ctx[((size_t)b * S + q) * DM + h * D + d] = f2bf_bits(cacc[dt][r]);
        }
}

// ---------------------------------------------------------------------------
extern "C" void kernel_launch(void* const* d_in, const int* in_sizes, int n_in,
                              void* d_out, int out_size, void* d_ws, size_t ws_size,
                              hipStream_t stream) {
    const float* q = (const float*)d_in[0];
    const float* k = (const float*)d_in[1];
    const float* v = (const float*)d_in[2];
    const float* Wq = (const float*)d_in[3];
    const float* Wk = (const float*)d_in[4];
    const float* Wv = (const float*)d_in[5];
    const float* Wo = (const float*)d_in[6];

    float* out = (float*)d_out;
    float* attn = out + (size_t)B * S * DM; // output 1 region

    const size_t NQ = (size_t)B * H * S * D; // 4.19M elements
    uint16_t* Qb = (uint16_t*)d_ws;
    uint16_t* Kb = Qb + NQ;
    uint16_t* Vt = Kb + NQ;
    uint16_t* ctx = Vt + NQ;

    dim3 gg(M / 128, DM / 128); // 32 x 8
    gemm_bt<1, 0><<<gg, 256, 0, stream>>>(q, Wq, Qb);
    gemm_bt<1, 0><<<gg, 256, 0, stream>>>(k, Wk, Kb);
    gemm_bt<1, 1><<<gg, 256, 0, stream>>>(v, Wv, Vt);
    attn_fused<<<dim3(S / 64, B * H), 256, 0, stream>>>(Qb, Kb, Vt, attn, ctx);
    gemm_bt<0, 2><<<gg, 256, 0, stream>>>(ctx, Wo, out);
}

// Round 2
// 561.932 us; speedup vs baseline: 1.1719x; 1.1719x over previous
//
#include <hip/hip_runtime.h>
#include <hip/hip_bf16.h>
#include <stdint.h>

// ---------------------------------------------------------------------------
// MHA: out = (softmax((xWq^T)(xWk^T)^T / 8) (xWv^T)) Wo^T  + attn matrix out
// B=4 S=1024 H=16 D=64 DM=1024.
// d_out = [ out (B,S,DM) fp32 | attn (B,H,S,S) fp32 ]
// ws    = [ Qb | Kb | Vt | ctx ] (bf16, 8MB ea) + [ Wq|Wk|Wv|Wo bf16 2MB ea ]
// ---------------------------------------------------------------------------

#define DEV static __device__ __forceinline__

typedef __bf16 bf16x8 __attribute__((ext_vector_type(8)));
typedef float f32x4 __attribute__((ext_vector_type(4)));
typedef unsigned short u16x8 __attribute__((ext_vector_type(8)));

static constexpr int B = 4, S = 1024, H = 16, D = 64, DM = 1024;
static constexpr int M = B * S; // 4096

DEV uint16_t f2bf_bits(float f) {
    __hip_bfloat16 h = __float2bfloat16(f); // RNE
    return __builtin_bit_cast(uint16_t, h);
}
DEV uint64_t pack4(float4 v) {
    return (uint64_t)f2bf_bits(v.x) | ((uint64_t)f2bf_bits(v.y) << 16) |
           ((uint64_t)f2bf_bits(v.z) << 32) | ((uint64_t)f2bf_bits(v.w) << 48);
}
DEV bf16x8 ldfrag(const uint16_t* p) { // p must be 16B aligned
    u16x8 t = *(const u16x8*)p;
    return __builtin_bit_cast(bf16x8, t);
}

#define GLOAD16(g, l)                                                  \
    __builtin_amdgcn_global_load_lds(                                  \
        (const __attribute__((address_space(1))) void*)(g),            \
        (__attribute__((address_space(3))) void*)(l), 16, 0, 0)

#define MFMA16(a, b, c) __builtin_amdgcn_mfma_f32_16x16x32_bf16(a, b, c, 0, 0, 0)

// ---------------------------------------------------------------------------
// Convert the 4 weight matrices fp32 -> bf16.  grid (512, 4), block 256.
// ---------------------------------------------------------------------------
__global__ __launch_bounds__(256) void cvt_w4(const float* __restrict__ w0,
                                              const float* __restrict__ w1,
                                              const float* __restrict__ w2,
                                              const float* __restrict__ w3,
                                              uint16_t* __restrict__ dst) {
    const float* srcs[4] = {w0, w1, w2, w3};
    const float* src = srcs[blockIdx.y];
    uint16_t* d = dst + (size_t)blockIdx.y * DM * DM;
    int i = (blockIdx.x * 256 + threadIdx.x) * 8;
    float4 a = *(const float4*)(src + i);
    float4 b = *(const float4*)(src + i + 4);
    *(uint64_t*)(d + i) = pack4(a);
    *(uint64_t*)(d + i + 4) = pack4(b);
}

// ---------------------------------------------------------------------------
// Fused QKV projection GEMM: C[m,n] = sum_k A[m,k] * W[n,k].
// grid (32, 8, 3): z selects (A, W, output).  A fp32 (reg-convert staging),
// W bf16 via global_load_lds.  z=0,1 -> (B,H,S,D) bf16; z=2 -> (B,H,D,S).
// ---------------------------------------------------------------------------
__global__ __launch_bounds__(256) void gemm_qkv(const float* __restrict__ qa,
                                                const float* __restrict__ ka,
                                                const float* __restrict__ va,
                                                const uint16_t* __restrict__ Wb,
                                                uint16_t* __restrict__ Qb,
                                                uint16_t* __restrict__ Kb,
                                                uint16_t* __restrict__ Vt) {
    constexpr int BK = 32;
    __shared__ uint16_t Ah[128 * BK];
    __shared__ uint16_t Bh[128 * BK];
    const int tid = threadIdx.x;
    const int lane = tid & 63, wid = tid >> 6;
    const int lr = lane & 15, lg = lane >> 4;
    const int m0 = blockIdx.x * 128, n0 = blockIdx.y * 128;
    const int z = blockIdx.z;
    const int wr = (wid >> 1) * 64, wc = (wid & 1) * 64;

    const float* A = z == 0 ? qa : (z == 1 ? ka : va);
    const uint16_t* W = Wb + (size_t)z * DM * DM;
    uint16_t* Cp = z == 0 ? Qb : (z == 1 ? Kb : Vt);

    // staging indices
    const int arow = tid >> 1, acs = (tid & 1) * 16;          // A: 1 row-half/thread
    const int brow = wid * 16 + (lane >> 2), bcol = (lane & 3) * 8; // B: gload

    f32x4 acc[4][4] = {};

    for (int kb = 0; kb < DM / BK; ++kb) {
        // ---- stage A tile (128 x 32) fp32 -> bf16 ----
        const float* ap = A + (size_t)(m0 + arow) * DM + kb * BK + acs;
        float4 v0 = *(const float4*)(ap + 0);
        float4 v1 = *(const float4*)(ap + 4);
        float4 v2 = *(const float4*)(ap + 8);
        float4 v3 = *(const float4*)(ap + 12);
        // ---- stage W tile (128 x 32) via global_load_lds ----
#pragma unroll
        for (int c = 0; c < 2; ++c) {
            int row = c * 64 + brow;
            GLOAD16(W + (size_t)(n0 + row) * DM + kb * BK + bcol, Bh + row * BK + bcol);
        }
        uint16_t* aw = Ah + arow * BK + acs;
        *(uint64_t*)(aw + 0) = pack4(v0);
        *(uint64_t*)(aw + 4) = pack4(v1);
        *(uint64_t*)(aw + 8) = pack4(v2);
        *(uint64_t*)(aw + 12) = pack4(v3);
        __syncthreads();

        bf16x8 af[4], bw[4];
#pragma unroll
        for (int i = 0; i < 4; ++i) af[i] = ldfrag(&Ah[(wr + i * 16 + lr) * BK + lg * 8]);
#pragma unroll
        for (int i = 0; i < 4; ++i) bw[i] = ldfrag(&Bh[(wc + i * 16 + lr) * BK + lg * 8]);
#pragma unroll
        for (int mi = 0; mi < 4; ++mi)
#pragma unroll
            for (int ni = 0; ni < 4; ++ni)
                acc[mi][ni] = MFMA16(af[mi], bw[ni], acc[mi][ni]);
        __syncthreads();
    }

    // ---- epilogue: C/D layout col=lane&15, row=(lane>>4)*4+r ----
#pragma unroll
    for (int mi = 0; mi < 4; ++mi)
#pragma unroll
        for (int ni = 0; ni < 4; ++ni)
#pragma unroll
            for (int r = 0; r < 4; ++r) {
                int gm = m0 + wr + mi * 16 + lg * 4 + r;
                int gn = n0 + wc + ni * 16 + lr;
                uint16_t v = f2bf_bits(acc[mi][ni][r]);
                int b = gm >> 10, s = gm & 1023, h = gn >> 6, d = gn & 63;
                if (z != 2)
                    Cp[((size_t)(b * H + h) * S + s) * D + d] = v;
                else
                    Cp[((size_t)(b * H + h) * D + d) * S + s] = v;
            }
}

// ---------------------------------------------------------------------------
// O GEMM: out = ctx @ Wo^T, both bf16 via global_load_lds, fp32 out.
// grid (32, 8).
// ---------------------------------------------------------------------------
__global__ __launch_bounds__(256) void gemm_o(const uint16_t* __restrict__ ctx,
                                              const uint16_t* __restrict__ Wo,
                                              float* __restrict__ out) {
    constexpr int BK = 32;
    __shared__ uint16_t Ah[128 * BK];
    __shared__ uint16_t Bh[128 * BK];
    const int tid = threadIdx.x;
    const int lane = tid & 63, wid = tid >> 6;
    const int lr = lane & 15, lg = lane >> 4;
    const int m0 = blockIdx.x * 128, n0 = blockIdx.y * 128;
    const int wr = (wid >> 1) * 64, wc = (wid & 1) * 64;
    const int srow = wid * 16 + (lane >> 2), scol = (lane & 3) * 8;

    f32x4 acc[4][4] = {};

    for (int kb = 0; kb < DM / BK; ++kb) {
#pragma unroll
        for (int c = 0; c < 2; ++c) {
            int row = c * 64 + srow;
            GLOAD16(ctx + (size_t)(m0 + row) * DM + kb * BK + scol, Ah + row * BK + scol);
            GLOAD16(Wo + (size_t)(n0 + row) * DM + kb * BK + scol, Bh + row * BK + scol);
        }
        __syncthreads();

        bf16x8 af[4], bw[4];
#pragma unroll
        for (int i = 0; i < 4; ++i) af[i] = ldfrag(&Ah[(wr + i * 16 + lr) * BK + lg * 8]);
#pragma unroll
        for (int i = 0; i < 4; ++i) bw[i] = ldfrag(&Bh[(wc + i * 16 + lr) * BK + lg * 8]);
#pragma unroll
        for (int mi = 0; mi < 4; ++mi)
#pragma unroll
            for (int ni = 0; ni < 4; ++ni)
                acc[mi][ni] = MFMA16(af[mi], bw[ni], acc[mi][ni]);
        __syncthreads();
    }

#pragma unroll
    for (int mi = 0; mi < 4; ++mi)
#pragma unroll
        for (int ni = 0; ni < 4; ++ni)
#pragma unroll
            for (int r = 0; r < 4; ++r) {
                int gm = m0 + wr + mi * 16 + lg * 4 + r;
                int gn = n0 + wc + ni * 16 + lr;
                out[(size_t)gm * DM + gn] = acc[mi][ni][r];
            }
}

// ---------------------------------------------------------------------------
// Fused attention.  Flat grid 1024, XCD-swizzled so all 16 q-tiles of a head
// (and 8 heads) share one XCD's L2 (K+V = 2MB resident).  4 waves x 16 q-rows.
// Pass 1: lsum.  Pass 2: recompute, write attn fp32, PV via LDS frag shuffle.
// ---------------------------------------------------------------------------
__global__ __launch_bounds__(256) void attn_fused(const uint16_t* __restrict__ Qb,
                                                  const uint16_t* __restrict__ Kb,
                                                  const uint16_t* __restrict__ Vt,
                                                  float* __restrict__ attn,
                                                  uint16_t* __restrict__ ctx) {
    __shared__ uint16_t plds[4][16][40];
    const int tid = threadIdx.x, lane = tid & 63, wid = tid >> 6;
    const int lr = lane & 15, lg = lane >> 4;
    // XCD-bijective decode: xcd = wg%8 (HW round-robin); bh%8 == xcd
    const int wg = blockIdx.x;
    const int xcd = wg & 7, rr_ = wg >> 3;
    const int qt = rr_ & 15, bh = xcd + 8 * (rr_ >> 4);
    const int q0 = qt * 64 + wid * 16;

    const uint16_t* Qp = Qb + ((size_t)bh * S + q0) * D;
    const bf16x8 aq0 = ldfrag(Qp + lr * D + lg * 8);
    const bf16x8 aq1 = ldfrag(Qp + lr * D + 32 + lg * 8);

    const uint16_t* Kbase = Kb + (size_t)bh * S * D;
    constexpr float CEXP = 0.125f * 1.44269504088896340736f; // (1/sqrt(D))*log2(e)

    // ---- pass 1: row sums of exp ----
    float lsum[4] = {0.f, 0.f, 0.f, 0.f};
    for (int kc = 0; kc < S / 32; ++kc) {
        const uint16_t* Kp = Kbase + (size_t)kc * 32 * D;
        bf16x8 k00 = ldfrag(Kp + lr * D + lg * 8);
        bf16x8 k01 = ldfrag(Kp + lr * D + 32 + lg * 8);
        bf16x8 k10 = ldfrag(Kp + (16 + lr) * D + lg * 8);
        bf16x8 k11 = ldfrag(Kp + (16 + lr) * D + 32 + lg * 8);
        f32x4 s0 = {}, s1 = {};
        s0 = MFMA16(aq0, k00, s0);
        s0 = MFMA16(aq1, k01, s0);
        s1 = MFMA16(aq0, k10, s1);
        s1 = MFMA16(aq1, k11, s1);
#pragma unroll
        for (int r = 0; r < 4; ++r)
            lsum[r] += exp2f(s0[r] * CEXP) + exp2f(s1[r] * CEXP);
    }
#pragma unroll
    for (int r = 0; r < 4; ++r) {
        float v = lsum[r];
        v += __shfl_xor(v, 1);
        v += __shfl_xor(v, 2);
        v += __shfl_xor(v, 4);
        v += __shfl_xor(v, 8);
        lsum[r] = 1.0f / v;
    }

    // ---- pass 2: attn write + PV ----
    f32x4 cacc[4] = {};
    float* attn_base = attn + (size_t)bh * S * S + (size_t)q0 * S;
    const uint16_t* Vbase = Vt + (size_t)bh * D * S;
    uint16_t(*pw)[40] = plds[wid];

    for (int kc = 0; kc < S / 32; ++kc) {
        const uint16_t* Kp = Kbase + (size_t)kc * 32 * D;
        bf16x8 k00 = ldfrag(Kp + lr * D + lg * 8);
        bf16x8 k01 = ldfrag(Kp + lr * D + 32 + lg * 8);
        bf16x8 k10 = ldfrag(Kp + (16 + lr) * D + lg * 8);
        bf16x8 k11 = ldfrag(Kp + (16 + lr) * D + 32 + lg * 8);
        bf16x8 bv[4];
#pragma unroll
        for (int dt = 0; dt < 4; ++dt)
            bv[dt] = ldfrag(Vbase + (size_t)(dt * 16 + lr) * S + kc * 32 + lg * 8);
        f32x4 s0 = {}, s1 = {};
        s0 = MFMA16(aq0, k00, s0);
        s0 = MFMA16(aq1, k01, s0);
        s1 = MFMA16(aq0, k10, s1);
        s1 = MFMA16(aq1, k11, s1);
#pragma unroll
        for (int r = 0; r < 4; ++r) {
            float p0 = exp2f(s0[r] * CEXP) * lsum[r];
            float p1 = exp2f(s1[r] * CEXP) * lsum[r];
            attn_base[(size_t)(lg * 4 + r) * S + kc * 32 + lr] = p0;
            attn_base[(size_t)(lg * 4 + r) * S + kc * 32 + 16 + lr] = p1;
            pw[lg * 4 + r][lr] = f2bf_bits(p0);
            pw[lg * 4 + r][16 + lr] = f2bf_bits(p1);
        }
        asm volatile("s_waitcnt lgkmcnt(0)" ::: "memory");
        bf16x8 pa = ldfrag(&pw[lr][lg * 8]);
#pragma unroll
        for (int dt = 0; dt < 4; ++dt)
            cacc[dt] = MFMA16(pa, bv[dt], cacc[dt]);
    }

    // ---- ctx store (B,S,DM) bf16 ----
    const int b = bh >> 4, h = bh & 15;
#pragma unroll
    for (int dt = 0; dt < 4; ++dt)
#pragma unroll
        for (int r = 0; r < 4; ++r) {
            int q = q0 + lg * 4 + r;
            int d = dt * 16 + lr;
            ctx[((size_t)b * S + q) * DM + h * D + d] = f2bf_bits(cacc[dt][r]);
        }
}

// ---------------------------------------------------------------------------
extern "C" void kernel_launch(void* const* d_in, const int* in_sizes, int n_in,
                              void* d_out, int out_size, void* d_ws, size_t ws_size,
                              hipStream_t stream) {
    const float* q = (const float*)d_in[0];
    const float* k = (const float*)d_in[1];
    const float* v = (const float*)d_in[2];
    const float* Wq = (const float*)d_in[3];
    const float* Wk = (const float*)d_in[4];
    const float* Wv = (const float*)d_in[5];
    const float* Wo = (const float*)d_in[6];

    float* out = (float*)d_out;
    float* attn = out + (size_t)B * S * DM;

    const size_t NQ = (size_t)B * H * S * D; // 4.19M
    uint16_t* Qb = (uint16_t*)d_ws;
    uint16_t* Kb = Qb + NQ;
    uint16_t* Vt = Kb + NQ;
    uint16_t* ctx = Vt + NQ;
    uint16_t* Wb = ctx + NQ; // 4 x DM*DM bf16 (Wq,Wk,Wv,Wo)

    cvt_w4<<<dim3(512, 4), 256, 0, stream>>>(Wq, Wk, Wv, Wo, Wb);
    gemm_qkv<<<dim3(M / 128, DM / 128, 3), 256, 0, stream>>>(q, k, v, Wb, Qb, Kb, Vt);
    attn_fused<<<dim3(16 * 64), 256, 0, stream>>>(Qb, Kb, Vt, attn, ctx);
    gemm_o<<<dim3(M / 128, DM / 128), 256, 0, stream>>>(ctx, Wb + (size_t)3 * DM * DM, out);
}

// Round 4
// 456.924 us; speedup vs baseline: 1.4412x; 1.2298x over previous
//
#include <hip/hip_runtime.h>
#include <hip/hip_bf16.h>
#include <stdint.h>

// ---------------------------------------------------------------------------
// MHA: out = (softmax((xWq^T)(xWk^T)^T / 8) (xWv^T)) Wo^T  + attn matrix out
// B=4 S=1024 H=16 D=64 DM=1024.
// d_out = [ out (B,S,DM) fp32 | attn (B,H,S,S) fp32 ]
// ws (big, >=59MB): [ xq xk xv | Wb(4) | Qb Kb Vt ] bf16, ctx overlays xq.
// ws (small):      [ Qb Kb Vt ctx | Wb(4) ] bf16 (42MB, round-2 proven).
// ---------------------------------------------------------------------------

#define DEV static __device__ __forceinline__

typedef __bf16 bf16x8 __attribute__((ext_vector_type(8)));
typedef float f32x4 __attribute__((ext_vector_type(4)));
typedef unsigned short u16x8 __attribute__((ext_vector_type(8)));

static constexpr int B = 4, S = 1024, H = 16, D = 64, DM = 1024, M = 4096;
static constexpr size_t NQ = (size_t)M * DM; // 4194304 elements

DEV uint16_t f2bf_bits(float f) {
    __hip_bfloat16 h = __float2bfloat16(f); // RNE
    return __builtin_bit_cast(uint16_t, h);
}
DEV uint64_t pack4(float4 v) {
    return (uint64_t)f2bf_bits(v.x) | ((uint64_t)f2bf_bits(v.y) << 16) |
           ((uint64_t)f2bf_bits(v.z) << 32) | ((uint64_t)f2bf_bits(v.w) << 48);
}
DEV uint64_t pack4f(const f32x4& v) {
    return (uint64_t)f2bf_bits(v[0]) | ((uint64_t)f2bf_bits(v[1]) << 16) |
           ((uint64_t)f2bf_bits(v[2]) << 32) | ((uint64_t)f2bf_bits(v[3]) << 48);
}
DEV bf16x8 ldfrag(const uint16_t* p) { // p must be 16B aligned
    u16x8 t = *(const u16x8*)p;
    return __builtin_bit_cast(bf16x8, t);
}

#define GLOAD16(g, l)                                                  \
    __builtin_amdgcn_global_load_lds(                                  \
        (const __attribute__((address_space(1))) void*)(g),            \
        (__attribute__((address_space(3))) void*)(l), 16, 0, 0)

#define MFMA16(a, b, c) __builtin_amdgcn_mfma_f32_16x16x32_bf16(a, b, c, 0, 0, 0)

// ---------------------------------------------------------------------------
// cvt_all (big ws): convert q,k,v,Wq,Wk,Wv,Wo fp32 -> bf16.  grid (2048, 7).
// ---------------------------------------------------------------------------
__global__ __launch_bounds__(256) void cvt_all(const float* __restrict__ q,
                                               const float* __restrict__ k,
                                               const float* __restrict__ v,
                                               const float* __restrict__ wq,
                                               const float* __restrict__ wk,
                                               const float* __restrict__ wv,
                                               const float* __restrict__ wo,
                                               uint16_t* __restrict__ dst) {
    const int y = blockIdx.y;
    const float* srcs[7] = {q, k, v, wq, wk, wv, wo};
    const float* src = srcs[y];
    const size_t base = y < 3 ? (size_t)y * NQ : 3 * NQ + (size_t)(y - 3) * (DM * DM);
    const size_t n = y < 3 ? NQ : (size_t)DM * DM;
    size_t i = ((size_t)blockIdx.x * 256 + threadIdx.x) * 8;
    if (i >= n) return;
    float4 a = *(const float4*)(src + i);
    float4 b2 = *(const float4*)(src + i + 4);
    *(uint64_t*)(dst + base + i) = pack4(a);
    *(uint64_t*)(dst + base + i + 4) = pack4(b2);
}

// cvt_w4 (small ws): weights only.  grid (512, 4).
__global__ __launch_bounds__(256) void cvt_w4(const float* __restrict__ w0,
                                              const float* __restrict__ w1,
                                              const float* __restrict__ w2,
                                              const float* __restrict__ w3,
                                              uint16_t* __restrict__ dst) {
    const float* srcs[4] = {w0, w1, w2, w3};
    const float* src = srcs[blockIdx.y];
    uint16_t* d = dst + (size_t)blockIdx.y * DM * DM;
    int i = (blockIdx.x * 256 + threadIdx.x) * 8;
    float4 a = *(const float4*)(src + i);
    float4 b2 = *(const float4*)(src + i + 4);
    *(uint64_t*)(d + i) = pack4(a);
    *(uint64_t*)(d + i + 4) = pack4(b2);
}

// ---------------------------------------------------------------------------
// QKV projection GEMM, m97-style: BK=64, W via global_load_lds.
// AF32=1: A fp32 reg-convert staging (padded LDS).  AF32=0: A bf16 gload.
// z=0,1 -> (B,H,S,D); z=2 -> (B,H,D,S) via LDS-transpose epilogue.
// ---------------------------------------------------------------------------
template <int AF32>
__global__ __launch_bounds__(256) void gemm_qkv(const float* __restrict__ qa,
                                                const float* __restrict__ ka,
                                                const float* __restrict__ va,
                                                const uint16_t* __restrict__ xb,
                                                const uint16_t* __restrict__ Wb,
                                                uint16_t* __restrict__ Qb,
                                                uint16_t* __restrict__ Kb,
                                                uint16_t* __restrict__ Vt) {
    constexpr int BK = 64, ALD = AF32 ? 72 : 64;
    __shared__ __align__(16) uint16_t smem[17408]; // Ah+Bh staging, or T
    uint16_t* Ah = smem;
    uint16_t* Bh = smem + (AF32 ? 9216 : 8192);
    const int tid = threadIdx.x, lane = tid & 63, wid = tid >> 6;
    const int lr = lane & 15, lg = lane >> 4;
    const int m0 = blockIdx.x * 128, n0 = blockIdx.y * 128, z = blockIdx.z;
    const int wr = (wid >> 1) * 64, wc = (wid & 1) * 64;

    const float* Af = z == 0 ? qa : (z == 1 ? ka : va);
    const uint16_t* Ab = xb + (size_t)z * NQ;
    const uint16_t* W = Wb + (size_t)z * (DM * DM);

    f32x4 acc[4][4] = {};

    for (int kb = 0; kb < DM / BK; ++kb) {
        if constexpr (AF32) {
#pragma unroll
            for (int i = 0; i < 8; ++i) {
                int f = tid + i * 256;
                int row = f >> 4, c4 = (f & 15) * 4;
                float4 vv = *(const float4*)(Af + (size_t)(m0 + row) * DM + kb * BK + c4);
                *(uint64_t*)&Ah[row * ALD + c4] = pack4(vv);
            }
        } else {
#pragma unroll
            for (int p = 0; p < 4; ++p) {
                int row = p * 32 + (tid >> 3), ce = (tid & 7) * 8;
                GLOAD16(Ab + (size_t)(m0 + row) * DM + kb * BK + ce, Ah + row * 64 + ce);
            }
        }
#pragma unroll
        for (int p = 0; p < 4; ++p) {
            int row = p * 32 + (tid >> 3), ce = (tid & 7) * 8;
            GLOAD16(W + (size_t)(n0 + row) * DM + kb * BK + ce, Bh + row * 64 + ce);
        }
        __syncthreads();

        bf16x8 af[4][2], bw[4][2];
#pragma unroll
        for (int i = 0; i < 4; ++i)
#pragma unroll
            for (int ks = 0; ks < 2; ++ks) {
                af[i][ks] = ldfrag(&Ah[(wr + i * 16 + lr) * ALD + ks * 32 + lg * 8]);
                bw[i][ks] = ldfrag(&Bh[(wc + i * 16 + lr) * 64 + ks * 32 + lg * 8]);
            }
#pragma unroll
        for (int ks = 0; ks < 2; ++ks)
#pragma unroll
            for (int mi = 0; mi < 4; ++mi)
#pragma unroll
                for (int ni = 0; ni < 4; ++ni)
                    acc[mi][ni] = MFMA16(af[mi][ks], bw[ni][ks], acc[mi][ni]);
        __syncthreads();
    }

    if (z != 2) {
        uint16_t* Cp = z == 0 ? Qb : Kb;
#pragma unroll
        for (int mi = 0; mi < 4; ++mi)
#pragma unroll
            for (int ni = 0; ni < 4; ++ni)
#pragma unroll
                for (int r = 0; r < 4; ++r) {
                    int gm = m0 + wr + mi * 16 + lg * 4 + r;
                    int gn = n0 + wc + ni * 16 + lr;
                    int b = gm >> 10, s = gm & 1023, h = gn >> 6, d = gn & 63;
                    Cp[((size_t)(b * H + h) * S + s) * D + d] = f2bf_bits(acc[mi][ni][r]);
                }
    } else {
        // ---- LDS-transpose epilogue: coalesced (B,H,D,S) stores ----
        uint16_t* T = smem; // [128 rows (d-major)][136] (272B stride, 16B-aligned)
#pragma unroll
        for (int mi = 0; mi < 4; ++mi)
#pragma unroll
            for (int ni = 0; ni < 4; ++ni) {
                int row = wc + ni * 16 + lr;       // gn local (h,d)
                int colb = wr + mi * 16 + lg * 4;  // gm local (s), 4 consecutive
                *(uint64_t*)&T[row * 136 + colb] = pack4f(acc[mi][ni]);
            }
        __syncthreads();
        const int b = m0 >> 10, s0b = m0 & 1023;
#pragma unroll
        for (int p = 0; p < 8; ++p) {
            int row = p * 16 + (tid >> 4), sl = tid & 15;
            int h = (n0 + row) >> 6, d = (n0 + row) & 63;
            u16x8 val = *(u16x8*)&T[row * 136 + sl * 8];
            *(u16x8*)&Vt[((size_t)(b * H + h) * D + d) * S + s0b + sl * 8] = val;
        }
    }
}

// ---------------------------------------------------------------------------
// O GEMM: out = ctx @ Wo^T, both bf16 gload, fp32 out.  grid (32, 8).
// ---------------------------------------------------------------------------
__global__ __launch_bounds__(256) void gemm_o(const uint16_t* __restrict__ ctx,
                                              const uint16_t* __restrict__ Wo,
                                              float* __restrict__ out) {
    constexpr int BK = 64;
    __shared__ __align__(16) uint16_t smem[16384];
    uint16_t* Ah = smem;
    uint16_t* Bh = smem + 8192;
    const int tid = threadIdx.x, lane = tid & 63, wid = tid >> 6;
    const int lr = lane & 15, lg = lane >> 4;
    const int m0 = blockIdx.x * 128, n0 = blockIdx.y * 128;
    const int wr = (wid >> 1) * 64, wc = (wid & 1) * 64;

    f32x4 acc[4][4] = {};

    for (int kb = 0; kb < DM / BK; ++kb) {
#pragma unroll
        for (int p = 0; p < 4; ++p) {
            int row = p * 32 + (tid >> 3), ce = (tid & 7) * 8;
            GLOAD16(ctx + (size_t)(m0 + row) * DM + kb * BK + ce, Ah + row * 64 + ce);
            GLOAD16(Wo + (size_t)(n0 + row) * DM + kb * BK + ce, Bh + row * 64 + ce);
        }
        __syncthreads();

        bf16x8 af[4][2], bw[4][2];
#pragma unroll
        for (int i = 0; i < 4; ++i)
#pragma unroll
            for (int ks = 0; ks < 2; ++ks) {
                af[i][ks] = ldfrag(&Ah[(wr + i * 16 + lr) * 64 + ks * 32 + lg * 8]);
                bw[i][ks] = ldfrag(&Bh[(wc + i * 16 + lr) * 64 + ks * 32 + lg * 8]);
            }
#pragma unroll
        for (int ks = 0; ks < 2; ++ks)
#pragma unroll
            for (int mi = 0; mi < 4; ++mi)
#pragma unroll
                for (int ni = 0; ni < 4; ++ni)
                    acc[mi][ni] = MFMA16(af[mi][ks], bw[ni][ks], acc[mi][ni]);
        __syncthreads();
    }

#pragma unroll
    for (int mi = 0; mi < 4; ++mi)
#pragma unroll
        for (int ni = 0; ni < 4; ++ni)
#pragma unroll
            for (int r = 0; r < 4; ++r) {
                int gm = m0 + wr + mi * 16 + lg * 4 + r;
                int gn = n0 + wc + ni * 16 + lr;
                out[(size_t)gm * DM + gn] = acc[mi][ni][r];
            }
}

// ---------------------------------------------------------------------------
// Fused attention v3.  1024 blocks (XCD-bijective swizzle), 4 waves x 16 rows.
// K/V double-buffered in LDS (swizzled-source gload, conflict-free frag reads).
// Pass 1: lsum.  Pass 2: p -> fp32 LDS -> float4 attn stores + bf16 PV frags.
// ---------------------------------------------------------------------------
__global__ __launch_bounds__(256) void attn_fused(const uint16_t* __restrict__ Qb,
                                                  const uint16_t* __restrict__ Kb,
                                                  const uint16_t* __restrict__ Vt,
                                                  float* __restrict__ attn,
                                                  uint16_t* __restrict__ ctx) {
    __shared__ __align__(16) uint16_t Kl[2][2048]; // 32 keys x 64 d, swizzled
    __shared__ __align__(16) uint16_t Vl[2][2048]; // 64 d x 32 keys, swizzled
    __shared__ __align__(16) float pf[4][16 * 36]; // per-wave p fp32 (16 q x 32 k)
    const int tid = threadIdx.x, lane = tid & 63, wid = tid >> 6;
    const int lr = lane & 15, lg = lane >> 4;
    const int wg = blockIdx.x;
    const int xcd = wg & 7, rr_ = wg >> 3;
    const int qt = rr_ & 15, bh = xcd + 8 * (rr_ >> 4);
    const int q0 = qt * 64 + wid * 16;

    const uint16_t* Qp = Qb + ((size_t)bh * S + q0) * D;
    const bf16x8 aq0 = ldfrag(Qp + lr * D + lg * 8);
    const bf16x8 aq1 = ldfrag(Qp + lr * D + 32 + lg * 8);

    const uint16_t* Kbase = Kb + (size_t)bh * S * D;
    const uint16_t* Vbase = Vt + (size_t)bh * D * S;
    constexpr float CEXP = 0.125f * 1.44269504088896340736f; // (1/sqrt(D))*log2(e)

    // staging: dest = linear (lane*16B), source pre-swizzled (m173 pattern)
    const int krow = tid >> 3, kslot = (tid & 7) ^ ((tid >> 3) & 7);
    const int vrow = tid >> 2, vslot = (tid & 3) ^ ((tid >> 3) & 3);

#define STAGE_K(buf, kc) GLOAD16(Kbase + (size_t)((kc)*32 + krow) * D + kslot * 8, &Kl[buf][tid * 8])
#define STAGE_V(buf, kc) GLOAD16(Vbase + (size_t)vrow * S + (kc)*32 + vslot * 8, &Vl[buf][tid * 8])
    // frag reads (swizzle-matched)
#define KFRAG(buf, t, h) ldfrag(&Kl[buf][((t)*16 + lr) * 64 + ((((h)*4 + lg) ^ (lr & 7)) * 8)])
#define VFRAG(buf, dt) ldfrag(&Vl[buf][((dt)*16 + lr) * 32 + ((lg ^ ((lr >> 1) & 3)) * 8)])

    // ---- pass 1: row sums of exp ----
    float lsum[4] = {0.f, 0.f, 0.f, 0.f};
    STAGE_K(0, 0);
    __syncthreads();
    for (int kc = 0; kc < S / 32; ++kc) {
        const int buf = kc & 1;
        if (kc < S / 32 - 1) STAGE_K(buf ^ 1, kc + 1);
        bf16x8 k00 = KFRAG(buf, 0, 0), k01 = KFRAG(buf, 0, 1);
        bf16x8 k10 = KFRAG(buf, 1, 0), k11 = KFRAG(buf, 1, 1);
        f32x4 s0 = {}, s1 = {};
        s0 = MFMA16(aq0, k00, s0);
        s0 = MFMA16(aq1, k01, s0);
        s1 = MFMA16(aq0, k10, s1);
        s1 = MFMA16(aq1, k11, s1);
#pragma unroll
        for (int r = 0; r < 4; ++r)
            lsum[r] += exp2f(s0[r] * CEXP) + exp2f(s1[r] * CEXP);
        __syncthreads();
    }
#pragma unroll
    for (int r = 0; r < 4; ++r) {
        float v = lsum[r];
        v += __shfl_xor(v, 1);
        v += __shfl_xor(v, 2);
        v += __shfl_xor(v, 4);
        v += __shfl_xor(v, 8);
        lsum[r] = 1.0f / v;
    }

    // ---- pass 2 ----
    f32x4 cacc[4] = {};
    float* attn_base = attn + (size_t)bh * S * S + (size_t)q0 * S;
    float* pfw = pf[wid];

    STAGE_K(0, 0);
    STAGE_V(0, 0);
    __syncthreads();
    for (int kc = 0; kc < S / 32; ++kc) {
        const int buf = kc & 1;
        if (kc < S / 32 - 1) {
            STAGE_K(buf ^ 1, kc + 1);
            STAGE_V(buf ^ 1, kc + 1);
        }
        bf16x8 k00 = KFRAG(buf, 0, 0), k01 = KFRAG(buf, 0, 1);
        bf16x8 k10 = KFRAG(buf, 1, 0), k11 = KFRAG(buf, 1, 1);
        f32x4 s0 = {}, s1 = {};
        s0 = MFMA16(aq0, k00, s0);
        s0 = MFMA16(aq1, k01, s0);
        s1 = MFMA16(aq0, k10, s1);
        s1 = MFMA16(aq1, k11, s1);
#pragma unroll
        for (int r = 0; r < 4; ++r) {
            pfw[(lg * 4 + r) * 36 + lr] = exp2f(s0[r] * CEXP) * lsum[r];
            pfw[(lg * 4 + r) * 36 + 16 + lr] = exp2f(s1[r] * CEXP) * lsum[r];
        }
        asm volatile("s_waitcnt lgkmcnt(0)" ::: "memory"); // wave-private pf ready
        // coalesced attn stores: lane -> row=lane>>2, 4 cols at (lane&3)*4 (+16)
        {
            const float* rp = &pfw[(lane >> 2) * 36 + (lane & 3) * 4];
            float4 a0 = *(const float4*)rp;
            float4 a1 = *(const float4*)(rp + 16);
            float* gp = attn_base + (size_t)(lane >> 2) * S + kc * 32 + (lane & 3) * 4;
            *(float4*)gp = a0;
            *(float4*)(gp + 16) = a1;
        }
        // PV A-fragment from pf (row=lr q-row, k=lg*8 keys)
        bf16x8 pa;
        {
            const f32x4 p0 = *(const f32x4*)&pfw[lr * 36 + lg * 8];
            const f32x4 p1 = *(const f32x4*)&pfw[lr * 36 + lg * 8 + 4];
            u16x8 pu;
#pragma unroll
            for (int j = 0; j < 4; ++j) {
                pu[j] = f2bf_bits(p0[j]);
                pu[4 + j] = f2bf_bits(p1[j]);
            }
            pa = __builtin_bit_cast(bf16x8, pu);
        }
#pragma unroll
        for (int dt = 0; dt < 4; ++dt) {
            bf16x8 bv = VFRAG(buf, dt);
            cacc[dt] = MFMA16(pa, bv, cacc[dt]);
        }
        __syncthreads();
    }

    // ---- ctx store (B,S,DM) bf16 ----
    const int b = bh >> 4, h = bh & 15;
#pragma unroll
    for (int dt = 0; dt < 4; ++dt)
#pragma unroll
        for (int r = 0; r < 4; ++r) {
            int q = q0 + lg * 4 + r;
            int d = dt * 16 + lr;
            ctx[((size_t)b * S + q) * DM + h * D + d] = f2bf_bits(cacc[dt][r]);
        }
#undef STAGE_K
#undef STAGE_V
#undef KFRAG
#undef VFRAG
}

// ---------------------------------------------------------------------------
extern "C" void kernel_launch(void* const* d_in, const int* in_sizes, int n_in,
                              void* d_out, int out_size, void* d_ws, size_t ws_size,
                              hipStream_t stream) {
    const float* q = (const float*)d_in[0];
    const float* k = (const float*)d_in[1];
    const float* v = (const float*)d_in[2];
    const float* Wq = (const float*)d_in[3];
    const float* Wk = (const float*)d_in[4];
    const float* Wv = (const float*)d_in[5];
    const float* Wo = (const float*)d_in[6];

    float* out = (float*)d_out;
    float* attn = out + (size_t)B * S * DM;

    const bool big = ws_size >= (size_t)7 * NQ * 2 + 256;
    dim3 gg(M / 128, DM / 128, 3);

    if (big) {
        uint16_t* xb = (uint16_t*)d_ws;      // 3*NQ (xq,xk,xv)
        uint16_t* Wb = xb + 3 * NQ;          // NQ   (Wq,Wk,Wv,Wo)
        uint16_t* Qb = Wb + NQ;
        uint16_t* Kb = Qb + NQ;
        uint16_t* Vt = Kb + NQ;
        uint16_t* ctx = xb; // xq dead after gemm_qkv
        cvt_all<<<dim3(2048, 7), 256, 0, stream>>>(q, k, v, Wq, Wk, Wv, Wo, xb);
        gemm_qkv<0><<<gg, 256, 0, stream>>>(q, k, v, xb, Wb, Qb, Kb, Vt);
        attn_fused<<<dim3(1024), 256, 0, stream>>>(Qb, Kb, Vt, attn, ctx);
        gemm_o<<<dim3(M / 128, DM / 128), 256, 0, stream>>>(ctx, Wb + (size_t)3 * DM * DM, out);
    } else {
        uint16_t* Qb = (uint16_t*)d_ws;
        uint16_t* Kb = Qb + NQ;
        uint16_t* Vt = Kb + NQ;
        uint16_t* ctx = Vt + NQ;
        uint16_t* Wb = ctx + NQ;
        cvt_w4<<<dim3(512, 4), 256, 0, stream>>>(Wq, Wk, Wv, Wo, Wb);
        gemm_qkv<1><<<gg, 256, 0, stream>>>(q, k, v, nullptr, Wb, Qb, Kb, Vt);
        attn_fused<<<dim3(1024), 256, 0, stream>>>(Qb, Kb, Vt, attn, ctx);
        gemm_o<<<dim3(M / 128, DM / 128), 256, 0, stream>>>(ctx, Wb + (size_t)3 * DM * DM, out);
    }
}